// Round 2
// 940.320 us; speedup vs baseline: 1.1696x; 1.1696x over previous
//
#include <hip/hip_runtime.h>
#include <stdint.h>

// R5 = R4 resubmit with defensive workspace layout. R4's theory: the 4.2M
// uncoalesced device-scope atomicAdds in k1's flush are ~268MB phantom FETCH +
// ~226MB phantom WRITE (memory-side line RMWs) -> replace with coalesced
// per-block partial stores (encpart[parts][8][32][512]) + part-reduction in k2.
// The R4 bench died at container level (no counters) -- possible OOB if
// ws_size < 17.4MB. Now: offsets computed at runtime; if ws_size is too small,
// fall back to the verified atomic path (parts=1, memset), identical to R0.

#define EPSV 1e-5f

constexpr int Bn = 8, Cn = 512, Kn = 32, Nn = 16384;
constexpr int TILE_N = 64;
constexpr int NBLK = 256, BLK_PER_B = NBLK / Bn;             // 32
constexpr int TILES_PER_BLK = (Nn / TILE_N) / BLK_PER_B;     // 8

typedef float f32x4 __attribute__((ext_vector_type(4)));
typedef __bf16 bf16x8 __attribute__((ext_vector_type(8)));
union U4B8 { uint4 u; bf16x8 b; };

__device__ __forceinline__ uint32_t f2bf(float f) {
  uint32_t u = __float_as_uint(f);
  u += 0x7fffu + ((u >> 16) & 1u);
  return u >> 16;
}
__device__ __forceinline__ float bflo(uint32_t d) { return __uint_as_float(d << 16); }
__device__ __forceinline__ float bfhi(uint32_t d) { return __uint_as_float(d & 0xffff0000u); }

__global__ void k0_prep(const float* __restrict__ conv_w, const float* __restrict__ codewords,
                        const float* __restrict__ g2, const float* __restrict__ b2,
                        const float* __restrict__ m2, const float* __restrict__ v2,
                        uint16_t* __restrict__ WT2, uint16_t* __restrict__ cwb,
                        float* __restrict__ c2, float* __restrict__ bns, float* __restrict__ bnb)
{
  const int idx = blockIdx.x * blockDim.x + threadIdx.x;  // 1024*256 = 262144
  if (idx < Cn * Cn) {
    const int o = idx >> 9, c = idx & 511;
    const int cc = c >> 5, cl = c & 31;
    WT2[((size_t)cc * 512 + o) * 32 + cl] = (uint16_t)f2bf(conv_w[idx]);
  }
  if (idx < Kn * Cn) cwb[idx] = (uint16_t)f2bf(codewords[idx]);
  if (idx < Cn) {
    const float s = g2[idx] * rsqrtf(v2[idx] + EPSV);
    bns[idx] = s;
    bnb[idx] = b2[idx] - m2[idx] * s;
  }
  if (idx < Kn) {
    float s = 0.f;
    for (int c = 0; c < Cn; ++c) { const float v = codewords[idx * 512 + c]; s = fmaf(v, v, s); }
    c2[idx] = s;
  }
}

__launch_bounds__(512, 2)
__global__ void k1_main(const float* __restrict__ x,
                        const uint16_t* __restrict__ WT2,
                        const uint16_t* __restrict__ cwb,
                        const float* __restrict__ bns, const float* __restrict__ bnb,
                        const float* __restrict__ c2g, const float* __restrict__ scaleg,
                        float* __restrict__ encpart, float* __restrict__ awsumpart,
                        int parts)
{
  __shared__ __align__(16) float    sXstage[32][65];  // 8.3 KB  f32 chunk [c][n], stride 65 (bank-spread)
  __shared__ __align__(16) uint16_t sXT[64][40];      // 5 KB    bf16 [n][c32], row 80B (b128-aligned)
  __shared__ __align__(16) uint16_t sF[64][520];      // 66.6 KB feat bf16 [n][c], row 1040B
  __shared__ __align__(16) uint16_t sCW[32][520];     // 33.3 KB codewords bf16 [k][c]
  __shared__ __align__(16) float    sAW[64][33];      // 8.4 KB  xc -> aw
  __shared__ float sX2[64];
  __shared__ float sBNs[512], sBNb[512];
  __shared__ float sScale[Kn], sC2[Kn];

  const int t    = threadIdx.x;
  const int lane = t & 63, w = t >> 6;       // 8 waves
  const int col  = lane & 15, quad = lane >> 4;
  const int b    = blockIdx.x / BLK_PER_B;
  const int tb0  = blockIdx.x % BLK_PER_B;

  // one-time staging: codewords (padded rows), BN params, scale/c2
  {
    const int row = t >> 4, seg = t & 15;    // 32 rows x 16 segs of 64B
    const uint4* src = (const uint4*)(cwb + row * 512 + seg * 32);
    uint4* dst = (uint4*)&sCW[row][seg * 32];
#pragma unroll
    for (int u = 0; u < 4; ++u) dst[u] = src[u];
    sBNs[t] = bns[t];
    sBNb[t] = bnb[t];
    if (t < Kn) { sScale[t] = scaleg[t]; sC2[t] = c2g[t]; }
  }

  float enc[32];
#pragma unroll
  for (int u = 0; u < 32; ++u) enc[u] = 0.f;
  float awacc = 0.f;
  const int k_e3 = t & 31, cg = t >> 5;      // E3: 32 k x 16 c-groups of 32

  for (int j = 0; j < TILES_PER_BLK; ++j) {
    const int n0 = (tb0 + j * BLK_PER_B) * TILE_N;

    f32x4 acc[4][4];
#pragma unroll
    for (int ot = 0; ot < 4; ++ot)
#pragma unroll
      for (int nt = 0; nt < 4; ++nt) acc[ot][nt] = (f32x4){0.f, 0.f, 0.f, 0.f};

    // prefetch chunk 0: A frags (global->reg) + x rows
    uint4 areg[2][4];
    float4 xreg;
    {
      const uint16_t* wp = WT2 + (w * 64 + col) * 32 + quad * 8;
#pragma unroll
      for (int ot = 0; ot < 4; ++ot) areg[0][ot] = *(const uint4*)(wp + ot * 512);
      xreg = *(const float4*)(x + ((size_t)(b * Cn) + (t >> 4)) * Nn + n0 + (t & 15) * 4);
    }

#pragma unroll
    for (int cc = 0; cc < 16; ++cc) {
      const int cur = cc & 1, nxt = cur ^ 1;
      __syncthreads();                                   // B1: protect sXstage/sXT
      {
        const int c_l = t >> 4, n4 = (t & 15) * 4;
        sXstage[c_l][n4 + 0] = xreg.x;
        sXstage[c_l][n4 + 1] = xreg.y;
        sXstage[c_l][n4 + 2] = xreg.z;
        sXstage[c_l][n4 + 3] = xreg.w;
      }
      __syncthreads();                                   // B2: sXstage visible
      {
        const int n = t >> 3, c4 = (t & 7) * 4;
        const float v0 = sXstage[c4 + 0][n], v1 = sXstage[c4 + 1][n];
        const float v2 = sXstage[c4 + 2][n], v3 = sXstage[c4 + 3][n];
        *(uint2*)&sXT[n][c4] = make_uint2(f2bf(v0) | (f2bf(v1) << 16),
                                          f2bf(v2) | (f2bf(v3) << 16));
      }
      if (cc + 1 < 16)
        xreg = *(const float4*)(x + ((size_t)(b * Cn) + (cc + 1) * 32 + (t >> 4)) * Nn + n0 + (t & 15) * 4);
      __syncthreads();                                   // B3: sXT visible
      if (cc + 1 < 16) {
        const uint16_t* wp = WT2 + (size_t)(cc + 1) * 16384 + (w * 64 + col) * 32 + quad * 8;
#pragma unroll
        for (int ot = 0; ot < 4; ++ot) areg[nxt][ot] = *(const uint4*)(wp + ot * 512);
      }
      U4B8 bfr[4];
#pragma unroll
      for (int nt = 0; nt < 4; ++nt) bfr[nt].u = *(const uint4*)&sXT[nt * 16 + col][quad * 8];
#pragma unroll
      for (int ot = 0; ot < 4; ++ot) {
        U4B8 a; a.u = areg[cur][ot];
#pragma unroll
        for (int nt = 0; nt < 4; ++nt)
          acc[ot][nt] = __builtin_amdgcn_mfma_f32_16x16x32_bf16(a.b, bfr[nt].b, acc[ot][nt], 0, 0, 0);
      }
    }

    // epilogue: BN2 + ReLU + bf16 pack -> sF[n][o]  (r-dim = 4 consecutive o -> b64)
#pragma unroll
    for (int ot = 0; ot < 4; ++ot) {
      const int ob = w * 64 + ot * 16 + quad * 4;
      const float4 s4 = *(const float4*)&sBNs[ob];
      const float4 b4 = *(const float4*)&sBNb[ob];
#pragma unroll
      for (int nt = 0; nt < 4; ++nt) {
        const f32x4 a = acc[ot][nt];
        const float r0 = fmaxf(fmaf(a[0], s4.x, b4.x), 0.f);
        const float r1 = fmaxf(fmaf(a[1], s4.y, b4.y), 0.f);
        const float r2 = fmaxf(fmaf(a[2], s4.z, b4.z), 0.f);
        const float r3 = fmaxf(fmaf(a[3], s4.w, b4.w), 0.f);
        *(uint2*)&sF[nt * 16 + col][ob] = make_uint2(f2bf(r0) | (f2bf(r1) << 16),
                                                     f2bf(r2) | (f2bf(r3) << 16));
      }
    }
    __syncthreads();                                     // B_e1: sF visible

    // x2: thread (n = t>>3, 64-c slice)
    {
      const int n = t >> 3, cb = (t & 7) * 64;
      float s = 0.f;
#pragma unroll
      for (int u = 0; u < 8; ++u) {
        const uint4 d = *(const uint4*)&sF[n][cb + u * 8];
        s = fmaf(bflo(d.x), bflo(d.x), s); s = fmaf(bfhi(d.x), bfhi(d.x), s);
        s = fmaf(bflo(d.y), bflo(d.y), s); s = fmaf(bfhi(d.y), bfhi(d.y), s);
        s = fmaf(bflo(d.z), bflo(d.z), s); s = fmaf(bfhi(d.z), bfhi(d.z), s);
        s = fmaf(bflo(d.w), bflo(d.w), s); s = fmaf(bfhi(d.w), bfhi(d.w), s);
      }
      s += __shfl_xor(s, 1); s += __shfl_xor(s, 2); s += __shfl_xor(s, 4);
      if ((t & 7) == 0) sX2[n] = s;
    }

    // E1: xc via MFMA — wave w handles tile (kt = w&1, nt = w>>1)
    {
      const int kt = w & 1, ntl = w >> 1;
      f32x4 xca = (f32x4){0.f, 0.f, 0.f, 0.f};
#pragma unroll
      for (int ks = 0; ks < 16; ++ks) {
        U4B8 af, bf;
        af.u = *(const uint4*)&sCW[kt * 16 + col][ks * 32 + quad * 8];
        bf.u = *(const uint4*)&sF[ntl * 16 + col][ks * 32 + quad * 8];
        xca = __builtin_amdgcn_mfma_f32_16x16x32_bf16(af.b, bf.b, xca, 0, 0, 0);
      }
#pragma unroll
      for (int r = 0; r < 4; ++r)
        sAW[ntl * 16 + col][kt * 16 + quad * 4 + r] = xca[r];
    }
    __syncthreads();                                     // B_e2: xc + x2 visible

    // softmax over K=32 per position (threads 0..63), logits built in-place
    if (t < 64) {
      const float x2v = sX2[t];
      float m = -1e30f;
#pragma unroll
      for (int k = 0; k < Kn; ++k) {
        const float l = sScale[k] * (x2v - 2.f * sAW[t][k] + sC2[k]);
        sAW[t][k] = l;
        m = fmaxf(m, l);
      }
      float s = 0.f;
#pragma unroll
      for (int k = 0; k < Kn; ++k) { const float e = __expf(sAW[t][k] - m); sAW[t][k] = e; s += e; }
      const float inv = 1.f / s;
#pragma unroll
      for (int k = 0; k < Kn; ++k) sAW[t][k] *= inv;
    }
    __syncthreads();                                     // B_e3: aw visible

    // E3: enc[k][c] += sum_n aw[n][k] * feat[n][c]
#pragma unroll 2
    for (int n = 0; n < TILE_N; ++n) {
      const float a = sAW[n][k_e3];
      if (cg == 0) awacc += a;
      const uint16_t* fp = &sF[n][cg * 32];
#pragma unroll
      for (int u = 0; u < 4; ++u) {
        const uint4 d = *(const uint4*)(fp + u * 8);
        enc[u*8+0] = fmaf(a, bflo(d.x), enc[u*8+0]);
        enc[u*8+1] = fmaf(a, bfhi(d.x), enc[u*8+1]);
        enc[u*8+2] = fmaf(a, bflo(d.y), enc[u*8+2]);
        enc[u*8+3] = fmaf(a, bfhi(d.y), enc[u*8+3]);
        enc[u*8+4] = fmaf(a, bflo(d.z), enc[u*8+4]);
        enc[u*8+5] = fmaf(a, bfhi(d.z), enc[u*8+5]);
        enc[u*8+6] = fmaf(a, bflo(d.w), enc[u*8+6]);
        enc[u*8+7] = fmaf(a, bfhi(d.w), enc[u*8+7]);
      }
    }
  }

  // flush: coalesced per-block partial stores if workspace allows (parts=32),
  // else the verified atomic fallback (parts=1).
  if (parts > 1) {
    float* dst = encpart + (((size_t)tb0 * Bn + b) * Kn + k_e3) * Cn + cg * 32;
#pragma unroll
    for (int u = 0; u < 8; ++u)
      *(float4*)(dst + u * 4) = make_float4(enc[u*4+0], enc[u*4+1], enc[u*4+2], enc[u*4+3]);
    if (cg == 0) awsumpart[((size_t)tb0 * Bn + b) * Kn + k_e3] = awacc;
  } else {
    float* dst = encpart + ((size_t)b * Kn + k_e3) * Cn + cg * 32;
#pragma unroll
    for (int u = 0; u < 32; ++u) atomicAdd(dst + u, enc[u]);
    if (cg == 0) atomicAdd(awsumpart + (size_t)b * Kn + k_e3, awacc);
  }
}

__global__ void k2_post(const float* __restrict__ encpart, const float* __restrict__ awsumpart,
                        const float* __restrict__ codewords,
                        const float* __restrict__ g1, const float* __restrict__ b1,
                        const float* __restrict__ m1, const float* __restrict__ v1,
                        const float* __restrict__ fc_w, const float* __restrict__ fc_b,
                        float* __restrict__ ef_out, float* __restrict__ gamma,
                        int parts)
{
  __shared__ float efs[Cn];
  __shared__ float saws[Kn];
  const int b = blockIdx.x, c = threadIdx.x;

  if (c < Kn) {
    float s = 0.f;
    for (int p = 0; p < parts; ++p) s += awsumpart[((size_t)p * Bn + b) * Kn + c];
    saws[c] = s;
  }
  __syncthreads();

  // part-reduction with 32-way MLP: 32 independent coalesced streams (lane = c)
  float esum[Kn];
#pragma unroll
  for (int k = 0; k < Kn; ++k) esum[k] = 0.f;
  for (int p = 0; p < parts; ++p) {
    const float* ep = encpart + (((size_t)p * Bn + b) * Kn) * Cn + c;
#pragma unroll
    for (int k = 0; k < Kn; ++k) esum[k] += ep[(size_t)k * Cn];
  }

  float s = 0.f;
#pragma unroll
  for (int k = 0; k < Kn; ++k) {
    float e = esum[k] - saws[k] * codewords[k * Cn + c];
    const float inv = rsqrtf(v1[k] + EPSV);
    e = (e - m1[k]) * (inv * g1[k]) + b1[k];
    s += fmaxf(e, 0.f);
  }
  s *= (1.f / 32.f);
  efs[c] = s;
  ef_out[b * Cn + c] = s;
  __syncthreads();
  const float4* w4 = (const float4*)(fc_w + (size_t)c * Cn);
  const float4* e4 = (const float4*)efs;
  float z = 0.f;
#pragma unroll 8
  for (int i = 0; i < Cn / 4; ++i) {
    const float4 w = w4[i], e = e4[i];
    z = fmaf(w.x, e.x, z); z = fmaf(w.y, e.y, z);
    z = fmaf(w.z, e.z, z); z = fmaf(w.w, e.w, z);
  }
  z += fc_b[c];
  gamma[b * Cn + c] = 1.f / (1.f + __expf(-z));
}

__global__ void k3_out(const float* __restrict__ x, const float* __restrict__ gamma,
                       float* __restrict__ out)
{
  const float4* x4 = (const float4*)x;
  float4* o4 = (float4*)out;
  int i = blockIdx.x * blockDim.x + threadIdx.x;
#pragma unroll
  for (int r = 0; r < 8; ++r, i += 2097152) {
    const int bb = i >> 21;
    const int cc = (i >> 12) & 511;
    const float g = 1.f + gamma[bb * 512 + cc];
    float4 v = x4[i];
    v.x = fmaxf(v.x * g, 0.f);
    v.y = fmaxf(v.y * g, 0.f);
    v.z = fmaxf(v.z * g, 0.f);
    v.w = fmaxf(v.w * g, 0.f);
    o4[i] = v;
  }
}

extern "C" void kernel_launch(void* const* d_in, const int* in_sizes, int n_in,
                              void* d_out, int out_size, void* d_ws, size_t ws_size,
                              hipStream_t stream) {
  const float* x      = (const float*)d_in[0];
  const float* conv_w = (const float*)d_in[1];
  const float* bn2g   = (const float*)d_in[2];
  const float* bn2b   = (const float*)d_in[3];
  const float* bn2m   = (const float*)d_in[4];
  const float* bn2v   = (const float*)d_in[5];
  const float* codew  = (const float*)d_in[6];
  const float* scale  = (const float*)d_in[7];
  const float* bn1g   = (const float*)d_in[8];
  const float* bn1b   = (const float*)d_in[9];
  const float* bn1m   = (const float*)d_in[10];
  const float* bn1v   = (const float*)d_in[11];
  const float* fc_w   = (const float*)d_in[12];
  const float* fc_b   = (const float*)d_in[13];

  // Runtime workspace layout. Partial path needs parts=32; fallback parts=1.
  const size_t enc_part_bytes = (size_t)BLK_PER_B * Bn * Kn * Cn * 4;  // 16,777,216
  const size_t aws_part_bytes = (size_t)BLK_PER_B * Bn * Kn * 4;       //     32,768
  const size_t enc_fall_bytes = (size_t)Bn * Kn * Cn * 4;              //    524,288
  const size_t aws_fall_bytes = (size_t)Bn * Kn * 4;                   //      1,024
  const size_t fixed_bytes = (size_t)Bn * Cn * 4      // gamma
                           + (size_t)Cn * Cn * 2      // WT2
                           + (size_t)Kn * Cn * 2      // cwb
                           + (size_t)Kn * 4           // c2
                           + (size_t)Cn * 4           // bns
                           + (size_t)Cn * 4;          // bnb
  const bool use_parts = ws_size >= enc_part_bytes + aws_part_bytes + fixed_bytes;
  const int parts = use_parts ? BLK_PER_B : 1;
  const size_t enc_bytes = use_parts ? enc_part_bytes : enc_fall_bytes;
  const size_t aws_bytes = use_parts ? aws_part_bytes : aws_fall_bytes;

  char* ws = (char*)d_ws;
  float*    encpart  = (float*)ws;                       ws += enc_bytes;
  float*    awsumpart= (float*)ws;                       ws += aws_bytes;
  float*    gamma    = (float*)ws;                       ws += (size_t)Bn * Cn * 4;
  uint16_t* WT2      = (uint16_t*)ws;                    ws += (size_t)Cn * Cn * 2;
  uint16_t* cwb      = (uint16_t*)ws;                    ws += (size_t)Kn * Cn * 2;
  float*    c2       = (float*)ws;                       ws += (size_t)Kn * 4;
  float*    bns      = (float*)ws;                       ws += (size_t)Cn * 4;
  float*    bnb      = (float*)ws;

  if (!use_parts)  // atomic fallback needs zeroed accumulators
    hipMemsetAsync(encpart, 0, enc_bytes + aws_bytes, stream);

  k0_prep<<<1024, 256, 0, stream>>>(conv_w, codew, bn2g, bn2b, bn2m, bn2v,
                                    WT2, cwb, c2, bns, bnb);
  k1_main<<<NBLK, 512, 0, stream>>>(x, WT2, cwb, bns, bnb, c2, scale,
                                    encpart, awsumpart, parts);
  k2_post<<<Bn, Cn, 0, stream>>>(encpart, awsumpart, codew, bn1g, bn1b, bn1m, bn1v,
                                 fc_w, fc_b, (float*)d_out, gamma, parts);
  k3_out<<<8192, 256, 0, stream>>>(x, gamma, (float*)d_out + Bn * Cn);
}